// Round 5
// baseline (1105.021 us; speedup 1.0000x reference)
//
#include <hip/hip_runtime.h>

// B=4, Cin=Cout=64, H=W=128, K=9, PAD=1. NCHW fp32.
//
// lgkm-only barrier: LDS producer->consumer needs lgkmcnt(0) only; global
// prefetch loads stay in flight across it (vmcnt wait lands at the use).
#define BAR_LGKM()                                         \
  do {                                                     \
    asm volatile("s_waitcnt lgkmcnt(0)" ::: "memory");     \
    __builtin_amdgcn_s_barrier();                          \
  } while (0)

// XCD-aware swizzle: 1024 blocks, 8 XCDs, dispatch round-robins bid%8.
// swz gives each XCD a contiguous 128-block chunk = 64 consecutive image
// rows -> gather footprint ~2.4MB fits the XCD's 4MB L2. Same mapping in
// both kernels so layer-1 writes are L2-warm for layer-2 reads.
// (Verified round 4: FETCH_SIZE 52.6 MB -> 12.7 MB.)
__device__ __forceinline__ int swz_block(int bid) {
  return ((bid & 7) << 7) + (bid >> 3);
}

// Workspace layout (floats):
//   wt1  @ 0       (36864)  main weights layer1, [c][og][k][oi] (og=o/8, oi=o%8)
//   wt2  @ 36864   (36864)
//   wo1  @ 73728   (10368)  offset-conv weights layer1, [c][t][j] (j=0..17)
//   wo2  @ 84096   (10368)
//   bn1  @ 94464   (128)    scale[64], shift[64]
//   bn2  @ 94592   (128)
//   offb @ 94720   (1179648)  4*18*16384
//   hbuf @ 1274368 (4194304)  4*64*16384

// ---------------- prep: weight relayouts + BN constants ---------------------
__global__ __launch_bounds__(256) void prep_kernel(
    const float* __restrict__ w1, const float* __restrict__ w2,
    const float* __restrict__ woff1, const float* __restrict__ woff2,
    const float* __restrict__ g1, const float* __restrict__ be1,
    const float* __restrict__ m1, const float* __restrict__ v1,
    const float* __restrict__ g2, const float* __restrict__ be2,
    const float* __restrict__ m2, const float* __restrict__ v2,
    float* __restrict__ ws) {
  float* wt1 = ws;
  float* wt2 = ws + 36864;
  float* wo1 = ws + 73728;
  float* wo2 = ws + 84096;
  float* bn1 = ws + 94464;
  float* bn2 = ws + 94592;
  int idx = blockIdx.x * 256 + threadIdx.x;
  if (idx < 73728) {
    int t = (idx < 36864) ? idx : idx - 36864;
    const float* w = (idx < 36864) ? w1 : w2;
    float* wt = (idx < 36864) ? wt1 : wt2;
    int oi = t & 7;
    int rest = t >> 3;             // (c*8+og)*9 + k
    int k = rest % 9;
    int cog = rest / 9;
    int og = cog & 7, c = cog >> 3;
    int o = og * 8 + oi;
    wt[t] = w[(o * 64 + c) * 9 + k];
  } else if (idx < 94464) {
    int u = idx - 73728;
    int t2 = (u < 10368) ? u : u - 10368;
    const float* w = (u < 10368) ? woff1 : woff2;
    float* wo = (u < 10368) ? wo1 : wo2;
    int j = t2 % 18;
    int v = t2 / 18;               // c*9 + t
    int tt = v % 9;
    int c = v / 9;
    wo[t2] = w[(j * 64 + c) * 9 + tt];
  } else if (idx < 94528) {
    int o = idx - 94464;
    float s = g1[o] * rsqrtf(v1[o] + 1e-5f);
    bn1[o] = s;
    bn1[64 + o] = be1[o] - m1[o] * s;
  } else if (idx < 94592) {
    int o = idx - 94528;
    float s = g2[o] * rsqrtf(v2[o] + 1e-5f);
    bn2[o] = s;
    bn2[64 + o] = be2[o] - m2[o] * s;
  }
}

// ---------------- offset conv: 3x3, 64 -> 18 ch, zero pad -------------------
// (unchanged from round 4 for clean A/B on dcn_main)
__global__ __launch_bounds__(512, 8) void conv_off_kernel(
    const float* __restrict__ xin, const float* __restrict__ wofft,
    const float* __restrict__ boff, float* __restrict__ off) {
  __shared__ float halo[2][792];   // [buf][plane*198 + pos], 4 planes/stage
  int tid = threadIdx.x;
  int pxl = tid & 63;
  int og = tid >> 6;
  int ogu = __builtin_amdgcn_readfirstlane(og);   // wave-uniform -> s_loads
  int p0 = swz_block(blockIdx.x) * 64;
  int b = p0 >> 14, hw0 = p0 & 16383;
  int h = hw0 >> 7, w0 = hw0 & 127;

  bool sv = tid < 396;
  int pp = (tid >= 198) ? 1 : 0;   // which of 2 plane-slots this thread loads
  int pos = tid - pp * 198;
  int r = pos / 66, cc = pos - r * 66;
  int yy = h + r - 1, xx = w0 + cc - 1;
  bool inb = sv && (yy >= 0) && (yy < 128) && (xx >= 0) && (xx < 128);
  int ofs = (yy << 7) + xx;        // plane-relative
  const float* xb0 = xin + ((size_t)(b * 64) << 14);

  // prologue: planes 0..3 (thread covers planes pp and 2+pp at its pos)
  float stg0 = inb ? xb0[((size_t)pp << 14) + ofs] : 0.f;
  float stg1 = inb ? xb0[((size_t)(2 + pp) << 14) + ofs] : 0.f;

  // j-channel assignment: og 0,1 -> 3 outputs; og 2..7 -> 2 outputs.
  int jbase = (ogu < 2) ? ogu * 3 : 6 + (ogu - 2) * 2;
  int nj = (ogu < 2) ? 3 : 2;
  int jc2 = jbase + 2;
  if (jc2 > 17) jc2 = 17;          // clamp (result unused when nj==2)

  float acc[3] = {0.f, 0.f, 0.f};

#pragma unroll 1
  for (int cg = 0; cg < 64; cg += 4) {
    int bufi = (cg >> 2) & 1;
    if (sv) {
      halo[bufi][pp * 198 + pos] = stg0;
      halo[bufi][(2 + pp) * 198 + pos] = stg1;
    }
    if (cg < 60) {
      stg0 = inb ? xb0[((size_t)(cg + 4 + pp) << 14) + ofs] : 0.f;
      stg1 = inb ? xb0[((size_t)(cg + 6 + pp) << 14) + ofs] : 0.f;
    }
    BAR_LGKM();
    const float* hb = halo[bufi];
#pragma unroll
    for (int p = 0; p < 4; ++p) {
      const float* wc = wofft + (cg + p) * 162;
#pragma unroll
      for (int t = 0; t < 9; ++t) {
        float v = hb[p * 198 + (t / 3) * 66 + pxl + (t % 3)];
        acc[0] = fmaf(v, wc[t * 18 + jbase], acc[0]);
        acc[1] = fmaf(v, wc[t * 18 + jbase + 1], acc[1]);
        acc[2] = fmaf(v, wc[t * 18 + jc2], acc[2]);
      }
    }
  }
#pragma unroll
  for (int i = 0; i < 3; ++i) {
    if (i < nj) {
      int j = jbase + i;
      off[((size_t)(b * 18 + j) << 14) + hw0 + pxl] = acc[i] + boff[j];
    }
  }
}

// ---------------- fused deformable sample + einsum + BN + ReLU --------------
// Block = 512 threads: 64 px x 8 o-groups (8 o each). 2-plane phases (32
// barriers). Per phase, LDS holds 1152 samples AND 1152 weights; weights
// reach the einsum via wave-uniform ds_read_b128 broadcast (2 LDS insts per
// 8 FMAs) instead of per-c s_load/VMEM — removes SGPR-pressure reissue.
// Samples: row-pair float2 gathers + cndmask select; taps + weights
// prefetched into regs one phase ahead (in flight across the lgkm barrier).
__global__ __launch_bounds__(512, 8) void dcn_main_kernel(
    const float* __restrict__ xin, const float* __restrict__ off,
    const float* __restrict__ wt, const float* __restrict__ bn,
    float* __restrict__ out) {
  __shared__ __align__(16) float sS[2][1152];   // samples [buf][p*576+slot]
  __shared__ __align__(16) float sW[2][1152];   // weights [buf][p*576+og*72+k*8+oi]
  int tid = threadIdx.x;
  int pxl = tid & 63;
  int og = tid >> 6;
  int ogu = __builtin_amdgcn_readfirstlane(og);
  int p0 = swz_block(blockIdx.x) * 64;
  int b = p0 >> 14, hw0 = p0 & 16383;
  int h = hw0 >> 7, w0 = hw0 & 127;
  const float* xb = xin + ((size_t)b << 20);

  bool act1 = (tid & 7) == 0;      // slot1 handled by 1/8 of threads
  int s1 = 512 + (tid >> 3);       // slot id 512..575 (k=8)
  bool wl = tid < 288;             // weight-staging threads (288*4 = 1152)

  // --- per-slot sampling params: row-pair base addrs + weights + selects ---
  float pw0[4], pw1[4];
  int ra0, rb0, ra1, rb1;          // (row<<7)+xb2 for rows y0,y1 of each slot
  bool se0a, se1a, se0b, se1b;

#pragma unroll
  for (int j = 0; j < 2; ++j) {
    bool a = (j == 0) || act1;
    int s = (j == 0) ? tid : s1;
    int k = s >> 6;
    int pxs = s & 63;
    int hw = hw0 + pxs;
    float dy = a ? off[((size_t)(b * 18 + 2 * k) << 14) + hw] : 0.f;
    float dx = a ? off[((size_t)(b * 18 + 2 * k + 1) << 14) + hw] : 0.f;
    float py = (float)(h + k / 3 - 1) + dy;
    float pxf = (float)(w0 + pxs + k % 3 - 1) + dx;
    float y0f = floorf(py), x0f = floorf(pxf);
    float wy1 = py - y0f, wx1 = pxf - x0f;
    float wy0 = 1.f - wy1, wx0 = 1.f - wx1;
    int y0 = (int)y0f, x0 = (int)x0f;
    int y1 = y0 + 1, x1 = x0 + 1;
    bool vy0 = (y0 >= 0) && (y0 <= 127);
    bool vy1 = (y1 >= 0) && (y1 <= 127);
    bool vx0 = (x0 >= 0) && (x0 <= 127);
    bool vx1 = (x1 >= 0) && (x1 <= 127);
    float* pw = (j == 0) ? pw0 : pw1;
    pw[0] = (vy0 && vx0) ? wy0 * wx0 : 0.f;
    pw[1] = (vy0 && vx1) ? wy0 * wx1 : 0.f;
    pw[2] = (vy1 && vx0) ? wy1 * wx0 : 0.f;
    pw[3] = (vy1 && vx1) ? wy1 * wx1 : 0.f;
    int y0c = min(max(y0, 0), 127), y1c = min(max(y1, 0), 127);
    int xb2 = min(max(x0, 0), 126);
    // tap(x0) = (x0==xb2)? v.x : v.y ; tap(x0+1) = (x0+1==xb2)? v.x : v.y
    // (whenever the select picks the "wrong" element, that corner weight is 0)
    if (j == 0) {
      ra0 = (y0c << 7) + xb2; rb0 = (y1c << 7) + xb2;
      se0a = (x0 == xb2); se1a = (x0 + 1 == xb2);
    } else {
      ra1 = (y0c << 7) + xb2; rb1 = (y1c << 7) + xb2;
      se0b = (x0 == xb2); se1b = (x0 + 1 == xb2);
    }
  }

  // prologue: tap sets A = taps(c=0), B = taps(c=1); weights for planes 0,1
  float2 A0, A1, A2, A3, B0, B1, B2, B3;
  A0 = *(const float2*)(xb + ra0);
  A1 = *(const float2*)(xb + rb0);
  A2 = act1 ? *(const float2*)(xb + ra1) : make_float2(0.f, 0.f);
  A3 = act1 ? *(const float2*)(xb + rb1) : make_float2(0.f, 0.f);
  {
    const float* x1p = xb + 16384;
    B0 = *(const float2*)(x1p + ra0);
    B1 = *(const float2*)(x1p + rb0);
    B2 = act1 ? *(const float2*)(x1p + ra1) : make_float2(0.f, 0.f);
    B3 = act1 ? *(const float2*)(x1p + rb1) : make_float2(0.f, 0.f);
  }
  float4 wreg = wl ? *(const float4*)(wt + (tid << 2)) : make_float4(0, 0, 0, 0);

  float acc[8];
#pragma unroll
  for (int oi = 0; oi < 8; ++oi) acc[oi] = 0.f;

#pragma unroll 1
  for (int c = 0; c < 64; c += 2) {
    int buf = (c >> 1) & 1;
    // stage this phase's weights (prefetched last phase) into LDS
    if (wl) *(float4*)&sW[buf][tid << 2] = wreg;
    // blend A -> plane 0 slots, B -> plane 1 slots
    {
      float v00 = se0a ? A0.x : A0.y;
      float v01 = se1a ? A0.x : A0.y;
      float v10 = se0a ? A1.x : A1.y;
      float v11 = se1a ? A1.x : A1.y;
      sS[buf][tid] = fmaf(pw0[0], v00,
                     fmaf(pw0[1], v01,
                     fmaf(pw0[2], v10, pw0[3] * v11)));
      v00 = se0a ? B0.x : B0.y;
      v01 = se1a ? B0.x : B0.y;
      v10 = se0a ? B1.x : B1.y;
      v11 = se1a ? B1.x : B1.y;
      sS[buf][576 + tid] = fmaf(pw0[0], v00,
                           fmaf(pw0[1], v01,
                           fmaf(pw0[2], v10, pw0[3] * v11)));
    }
    if (act1) {
      float v00 = se0b ? A2.x : A2.y;
      float v01 = se1b ? A2.x : A2.y;
      float v10 = se0b ? A3.x : A3.y;
      float v11 = se1b ? A3.x : A3.y;
      sS[buf][s1] = fmaf(pw1[0], v00,
                    fmaf(pw1[1], v01,
                    fmaf(pw1[2], v10, pw1[3] * v11)));
      v00 = se0b ? B2.x : B2.y;
      v01 = se1b ? B2.x : B2.y;
      v10 = se0b ? B3.x : B3.y;
      v11 = se1b ? B3.x : B3.y;
      sS[buf][576 + s1] = fmaf(pw1[0], v00,
                          fmaf(pw1[1], v01,
                          fmaf(pw1[2], v10, pw1[3] * v11)));
    }
    // prefetch next phase's taps + weights (in flight across the barrier)
    if (c < 62) {
      const float* xn = xb + ((size_t)(c + 2) << 14);
      A0 = *(const float2*)(xn + ra0);
      A1 = *(const float2*)(xn + rb0);
      if (act1) {
        A2 = *(const float2*)(xn + ra1);
        A3 = *(const float2*)(xn + rb1);
      }
      const float* xn2 = xn + 16384;
      B0 = *(const float2*)(xn2 + ra0);
      B1 = *(const float2*)(xn2 + rb0);
      if (act1) {
        B2 = *(const float2*)(xn2 + ra1);
        B3 = *(const float2*)(xn2 + rb1);
      }
      if (wl) wreg = *(const float4*)(wt + (c + 2) * 576 + (tid << 2));
    }
    BAR_LGKM();
    // einsum: 2 planes x 9k x 8o, weights via wave-uniform b128 broadcast
#pragma unroll
    for (int p = 0; p < 2; ++p) {
      const float* wb = &sW[buf][p * 576 + ogu * 72];
      const float* sb = &sS[buf][p * 576 + pxl];
#pragma unroll
      for (int k = 0; k < 9; ++k) {
        float4 wA = *(const float4*)(wb + k * 8);
        float4 wB = *(const float4*)(wb + k * 8 + 4);
        float sval = sb[k * 64];
        acc[0] = fmaf(sval, wA.x, acc[0]);
        acc[1] = fmaf(sval, wA.y, acc[1]);
        acc[2] = fmaf(sval, wA.z, acc[2]);
        acc[3] = fmaf(sval, wA.w, acc[3]);
        acc[4] = fmaf(sval, wB.x, acc[4]);
        acc[5] = fmaf(sval, wB.y, acc[5]);
        acc[6] = fmaf(sval, wB.z, acc[6]);
        acc[7] = fmaf(sval, wB.w, acc[7]);
      }
    }
  }

#pragma unroll
  for (int oi = 0; oi < 8; ++oi) {
    int o = ogu * 8 + oi;
    float rres = fmaf(acc[oi], bn[o], bn[64 + o]);
    out[((size_t)(b * 64 + o) << 14) + hw0 + pxl] = fmaxf(rres, 0.f);
  }
}

extern "C" void kernel_launch(void* const* d_in, const int* in_sizes, int n_in,
                              void* d_out, int out_size, void* d_ws, size_t ws_size,
                              hipStream_t stream) {
  const float* x      = (const float*)d_in[0];
  const float* w_off1 = (const float*)d_in[1];
  const float* b_off1 = (const float*)d_in[2];
  const float* w1     = (const float*)d_in[3];
  const float* g1     = (const float*)d_in[4];
  const float* be1    = (const float*)d_in[5];
  const float* m1     = (const float*)d_in[6];
  const float* v1     = (const float*)d_in[7];
  const float* w_off2 = (const float*)d_in[8];
  const float* b_off2 = (const float*)d_in[9];
  const float* w2     = (const float*)d_in[10];
  const float* g2     = (const float*)d_in[11];
  const float* be2    = (const float*)d_in[12];
  const float* m2     = (const float*)d_in[13];
  const float* v2     = (const float*)d_in[14];
  float* out = (float*)d_out;

  float* ws   = (float*)d_ws;
  float* wt1  = ws;
  float* wt2  = ws + 36864;
  float* wo1  = ws + 73728;
  float* wo2  = ws + 84096;
  float* bn1  = ws + 94464;
  float* bn2  = ws + 94592;
  float* offb = ws + 94720;
  float* hbuf = ws + 1274368;

  prep_kernel<<<370, 256, 0, stream>>>(w1, w2, w_off1, w_off2,
                                       g1, be1, m1, v1, g2, be2, m2, v2, ws);

  conv_off_kernel<<<1024, 512, 0, stream>>>(x, wo1, b_off1, offb);
  dcn_main_kernel<<<1024, 512, 0, stream>>>(x, offb, wt1, bn1, hbuf);

  conv_off_kernel<<<1024, 512, 0, stream>>>(hbuf, wo2, b_off2, offb);
  dcn_main_kernel<<<1024, 512, 0, stream>>>(hbuf, offb, wt2, bn2, out);
}

// Round 6
// 431.753 us; speedup vs baseline: 2.5594x; 2.5594x over previous
//
#include <hip/hip_runtime.h>

// B=4, Cin=Cout=64, H=W=128, K=9, PAD=1. NCHW fp32.
//
// lgkm-only barrier: LDS producer->consumer needs lgkmcnt(0) only; global
// prefetch loads stay in flight across it (vmcnt wait lands at the use).
#define BAR_LGKM()                                         \
  do {                                                     \
    asm volatile("s_waitcnt lgkmcnt(0)" ::: "memory");     \
    __builtin_amdgcn_s_barrier();                          \
  } while (0)

// XCD-aware swizzle: 1024 blocks, 8 XCDs, dispatch round-robins bid%8.
// Each XCD gets a contiguous 128-block chunk -> gather footprint ~2.4MB
// fits the XCD's 4MB L2. (Verified round 4: FETCH 52.6 MB -> 12.7 MB.)
__device__ __forceinline__ int swz_block(int bid) {
  return ((bid & 7) << 7) + (bid >> 3);
}

// Workspace layout (floats):
//   wt1  @ 0       (36864)  main weights layer1, [c][og][k][oi] (og=o/8, oi=o%8)
//   wt2  @ 36864   (36864)
//   wo1  @ 73728   (10368)  offset-conv weights layer1, [c][t][j] (j=0..17)
//   wo2  @ 84096   (10368)
//   bn1  @ 94464   (128)    scale[64], shift[64]
//   bn2  @ 94592   (128)
//   offb @ 94720   (1179648)  4*18*16384
//   hbuf @ 1274368 (4194304)  4*64*16384

// ---------------- prep: weight relayouts + BN constants ---------------------
__global__ __launch_bounds__(256) void prep_kernel(
    const float* __restrict__ w1, const float* __restrict__ w2,
    const float* __restrict__ woff1, const float* __restrict__ woff2,
    const float* __restrict__ g1, const float* __restrict__ be1,
    const float* __restrict__ m1, const float* __restrict__ v1,
    const float* __restrict__ g2, const float* __restrict__ be2,
    const float* __restrict__ m2, const float* __restrict__ v2,
    float* __restrict__ ws) {
  float* wt1 = ws;
  float* wt2 = ws + 36864;
  float* wo1 = ws + 73728;
  float* wo2 = ws + 84096;
  float* bn1 = ws + 94464;
  float* bn2 = ws + 94592;
  int idx = blockIdx.x * 256 + threadIdx.x;
  if (idx < 73728) {
    int t = (idx < 36864) ? idx : idx - 36864;
    const float* w = (idx < 36864) ? w1 : w2;
    float* wt = (idx < 36864) ? wt1 : wt2;
    int oi = t & 7;
    int rest = t >> 3;             // (c*8+og)*9 + k
    int k = rest % 9;
    int cog = rest / 9;
    int og = cog & 7, c = cog >> 3;
    int o = og * 8 + oi;
    wt[t] = w[(o * 64 + c) * 9 + k];
  } else if (idx < 94464) {
    int u = idx - 73728;
    int t2 = (u < 10368) ? u : u - 10368;
    const float* w = (u < 10368) ? woff1 : woff2;
    float* wo = (u < 10368) ? wo1 : wo2;
    int j = t2 % 18;
    int v = t2 / 18;               // c*9 + t
    int tt = v % 9;
    int c = v / 9;
    wo[t2] = w[(j * 64 + c) * 9 + tt];
  } else if (idx < 94528) {
    int o = idx - 94464;
    float s = g1[o] * rsqrtf(v1[o] + 1e-5f);
    bn1[o] = s;
    bn1[64 + o] = be1[o] - m1[o] * s;
  } else if (idx < 94592) {
    int o = idx - 94528;
    float s = g2[o] * rsqrtf(v2[o] + 1e-5f);
    bn2[o] = s;
    bn2[64 + o] = be2[o] - m2[o] * s;
  }
}

// ---------------- offset conv: 3x3, 64 -> 18 ch, zero pad -------------------
// (unchanged for clean A/B on dcn_main)
__global__ __launch_bounds__(512, 8) void conv_off_kernel(
    const float* __restrict__ xin, const float* __restrict__ wofft,
    const float* __restrict__ boff, float* __restrict__ off) {
  __shared__ float halo[2][792];   // [buf][plane*198 + pos], 4 planes/stage
  int tid = threadIdx.x;
  int pxl = tid & 63;
  int og = tid >> 6;
  int ogu = __builtin_amdgcn_readfirstlane(og);   // wave-uniform -> s_loads
  int p0 = swz_block(blockIdx.x) * 64;
  int b = p0 >> 14, hw0 = p0 & 16383;
  int h = hw0 >> 7, w0 = hw0 & 127;

  bool sv = tid < 396;
  int pp = (tid >= 198) ? 1 : 0;   // which of 2 plane-slots this thread loads
  int pos = tid - pp * 198;
  int r = pos / 66, cc = pos - r * 66;
  int yy = h + r - 1, xx = w0 + cc - 1;
  bool inb = sv && (yy >= 0) && (yy < 128) && (xx >= 0) && (xx < 128);
  int ofs = (yy << 7) + xx;        // plane-relative
  const float* xb0 = xin + ((size_t)(b * 64) << 14);

  // prologue: planes 0..3 (thread covers planes pp and 2+pp at its pos)
  float stg0 = inb ? xb0[((size_t)pp << 14) + ofs] : 0.f;
  float stg1 = inb ? xb0[((size_t)(2 + pp) << 14) + ofs] : 0.f;

  // j-channel assignment: og 0,1 -> 3 outputs; og 2..7 -> 2 outputs.
  int jbase = (ogu < 2) ? ogu * 3 : 6 + (ogu - 2) * 2;
  int nj = (ogu < 2) ? 3 : 2;
  int jc2 = jbase + 2;
  if (jc2 > 17) jc2 = 17;          // clamp (result unused when nj==2)

  float acc[3] = {0.f, 0.f, 0.f};

#pragma unroll 1
  for (int cg = 0; cg < 64; cg += 4) {
    int bufi = (cg >> 2) & 1;
    if (sv) {
      halo[bufi][pp * 198 + pos] = stg0;
      halo[bufi][(2 + pp) * 198 + pos] = stg1;
    }
    if (cg < 60) {
      stg0 = inb ? xb0[((size_t)(cg + 4 + pp) << 14) + ofs] : 0.f;
      stg1 = inb ? xb0[((size_t)(cg + 6 + pp) << 14) + ofs] : 0.f;
    }
    BAR_LGKM();
    const float* hb = halo[bufi];
#pragma unroll
    for (int p = 0; p < 4; ++p) {
      const float* wc = wofft + (cg + p) * 162;
#pragma unroll
      for (int t = 0; t < 9; ++t) {
        float v = hb[p * 198 + (t / 3) * 66 + pxl + (t % 3)];
        acc[0] = fmaf(v, wc[t * 18 + jbase], acc[0]);
        acc[1] = fmaf(v, wc[t * 18 + jbase + 1], acc[1]);
        acc[2] = fmaf(v, wc[t * 18 + jc2], acc[2]);
      }
    }
  }
#pragma unroll
  for (int i = 0; i < 3; ++i) {
    if (i < nj) {
      int j = jbase + i;
      off[((size_t)(b * 18 + j) << 14) + hw0 + pxl] = acc[i] + boff[j];
    }
  }
}

// ---------------- fused deformable sample + einsum + BN + ReLU --------------
// Block = 512 threads: 64 px x 8 o-groups (8 o each). 2-plane phases (32
// barriers). Weights reach the einsum via wave-uniform ds_read_b128 LDS
// broadcast (prefetched one phase ahead). launch_bounds(512,4): VGPR cap
// 128 — round 5's (512,8) cap of 64 forced a scratch spill (FETCH 820 MB,
// WRITE 943 MB of spill churn). 16-24 waves/CU is enough (round 1: 16 vs
// 32 waves was perf-neutral for this kernel).
__global__ __launch_bounds__(512, 4) void dcn_main_kernel(
    const float* __restrict__ xin, const float* __restrict__ off,
    const float* __restrict__ wt, const float* __restrict__ bn,
    float* __restrict__ out) {
  __shared__ __align__(16) float sS[2][1152];   // samples [buf][p*576+slot]
  __shared__ __align__(16) float sW[2][1152];   // weights [buf][p*576+og*72+k*8+oi]
  int tid = threadIdx.x;
  int pxl = tid & 63;
  int og = tid >> 6;
  int ogu = __builtin_amdgcn_readfirstlane(og);
  int p0 = swz_block(blockIdx.x) * 64;
  int b = p0 >> 14, hw0 = p0 & 16383;
  int h = hw0 >> 7, w0 = hw0 & 127;
  const float* xb = xin + ((size_t)b << 20);

  bool act1 = (tid & 7) == 0;      // slot1 handled by 1/8 of threads
  int s1 = 512 + (tid >> 3);       // slot id 512..575 (k=8)
  bool wl = tid < 288;             // weight-staging threads (288*4 = 1152)

  // --- per-slot sampling params (statically-unrolled array indexing only;
  //     no pointer-selects -> SROA keeps everything in registers) ---
  float pw[2][4];
  int ra[2], rb[2];                // (row<<7)+xb2 for rows y0,y1 of each slot
  bool se0[2], se1[2];

#pragma unroll
  for (int j = 0; j < 2; ++j) {
    bool a = (j == 0) || act1;
    int s = (j == 0) ? tid : s1;
    int k = s >> 6;
    int pxs = s & 63;
    int hw = hw0 + pxs;
    float dy = a ? off[((size_t)(b * 18 + 2 * k) << 14) + hw] : 0.f;
    float dx = a ? off[((size_t)(b * 18 + 2 * k + 1) << 14) + hw] : 0.f;
    float py = (float)(h + k / 3 - 1) + dy;
    float pxf = (float)(w0 + pxs + k % 3 - 1) + dx;
    float y0f = floorf(py), x0f = floorf(pxf);
    float wy1 = py - y0f, wx1 = pxf - x0f;
    float wy0 = 1.f - wy1, wx0 = 1.f - wx1;
    int y0 = (int)y0f, x0 = (int)x0f;
    int y1 = y0 + 1, x1 = x0 + 1;
    bool vy0 = (y0 >= 0) && (y0 <= 127);
    bool vy1 = (y1 >= 0) && (y1 <= 127);
    bool vx0 = (x0 >= 0) && (x0 <= 127);
    bool vx1 = (x1 >= 0) && (x1 <= 127);
    pw[j][0] = (vy0 && vx0) ? wy0 * wx0 : 0.f;
    pw[j][1] = (vy0 && vx1) ? wy0 * wx1 : 0.f;
    pw[j][2] = (vy1 && vx0) ? wy1 * wx0 : 0.f;
    pw[j][3] = (vy1 && vx1) ? wy1 * wx1 : 0.f;
    int y0c = min(max(y0, 0), 127), y1c = min(max(y1, 0), 127);
    int xb2 = min(max(x0, 0), 126);
    // tap(x0) = (x0==xb2)? v.x : v.y ; tap(x0+1) = (x0+1==xb2)? v.x : v.y
    // (whenever the select picks the "wrong" element, that corner weight is 0)
    ra[j] = (y0c << 7) + xb2;
    rb[j] = (y1c << 7) + xb2;
    se0[j] = (x0 == xb2);
    se1[j] = (x0 + 1 == xb2);
  }

  // prologue: tap sets A = taps(c=0), B = taps(c=1); weights for planes 0,1
  float2 A0, A1, A2, A3, B0, B1, B2, B3;
  A0 = *(const float2*)(xb + ra[0]);
  A1 = *(const float2*)(xb + rb[0]);
  A2 = act1 ? *(const float2*)(xb + ra[1]) : make_float2(0.f, 0.f);
  A3 = act1 ? *(const float2*)(xb + rb[1]) : make_float2(0.f, 0.f);
  {
    const float* x1p = xb + 16384;
    B0 = *(const float2*)(x1p + ra[0]);
    B1 = *(const float2*)(x1p + rb[0]);
    B2 = act1 ? *(const float2*)(x1p + ra[1]) : make_float2(0.f, 0.f);
    B3 = act1 ? *(const float2*)(x1p + rb[1]) : make_float2(0.f, 0.f);
  }
  float4 wreg = wl ? *(const float4*)(wt + (tid << 2)) : make_float4(0, 0, 0, 0);

  float acc[8];
#pragma unroll
  for (int oi = 0; oi < 8; ++oi) acc[oi] = 0.f;

#pragma unroll 1
  for (int c = 0; c < 64; c += 2) {
    int buf = (c >> 1) & 1;
    // stage this phase's weights (prefetched last phase) into LDS
    if (wl) *(float4*)&sW[buf][tid << 2] = wreg;
    // blend A -> plane 0 slots, B -> plane 1 slots
    {
      float v00 = se0[0] ? A0.x : A0.y;
      float v01 = se1[0] ? A0.x : A0.y;
      float v10 = se0[0] ? A1.x : A1.y;
      float v11 = se1[0] ? A1.x : A1.y;
      sS[buf][tid] = fmaf(pw[0][0], v00,
                     fmaf(pw[0][1], v01,
                     fmaf(pw[0][2], v10, pw[0][3] * v11)));
      v00 = se0[0] ? B0.x : B0.y;
      v01 = se1[0] ? B0.x : B0.y;
      v10 = se0[0] ? B1.x : B1.y;
      v11 = se1[0] ? B1.x : B1.y;
      sS[buf][576 + tid] = fmaf(pw[0][0], v00,
                           fmaf(pw[0][1], v01,
                           fmaf(pw[0][2], v10, pw[0][3] * v11)));
    }
    if (act1) {
      float v00 = se0[1] ? A2.x : A2.y;
      float v01 = se1[1] ? A2.x : A2.y;
      float v10 = se0[1] ? A3.x : A3.y;
      float v11 = se1[1] ? A3.x : A3.y;
      sS[buf][s1] = fmaf(pw[1][0], v00,
                    fmaf(pw[1][1], v01,
                    fmaf(pw[1][2], v10, pw[1][3] * v11)));
      v00 = se0[1] ? B2.x : B2.y;
      v01 = se1[1] ? B2.x : B2.y;
      v10 = se0[1] ? B3.x : B3.y;
      v11 = se1[1] ? B3.x : B3.y;
      sS[buf][576 + s1] = fmaf(pw[1][0], v00,
                          fmaf(pw[1][1], v01,
                          fmaf(pw[1][2], v10, pw[1][3] * v11)));
    }
    // prefetch next phase's taps + weights (in flight across the barrier)
    if (c < 62) {
      const float* xn = xb + ((size_t)(c + 2) << 14);
      A0 = *(const float2*)(xn + ra[0]);
      A1 = *(const float2*)(xn + rb[0]);
      if (act1) {
        A2 = *(const float2*)(xn + ra[1]);
        A3 = *(const float2*)(xn + rb[1]);
      }
      const float* xn2 = xn + 16384;
      B0 = *(const float2*)(xn2 + ra[0]);
      B1 = *(const float2*)(xn2 + rb[0]);
      if (act1) {
        B2 = *(const float2*)(xn2 + ra[1]);
        B3 = *(const float2*)(xn2 + rb[1]);
      }
      if (wl) wreg = *(const float4*)(wt + (c + 2) * 576 + (tid << 2));
    }
    BAR_LGKM();
    // einsum: 2 planes x 9k x 8o, weights via wave-uniform b128 broadcast
#pragma unroll
    for (int p = 0; p < 2; ++p) {
      const float* wb = &sW[buf][p * 576 + ogu * 72];
      const float* sb = &sS[buf][p * 576 + pxl];
#pragma unroll
      for (int k = 0; k < 9; ++k) {
        float4 wA = *(const float4*)(wb + k * 8);
        float4 wB = *(const float4*)(wb + k * 8 + 4);
        float sval = sb[k * 64];
        acc[0] = fmaf(sval, wA.x, acc[0]);
        acc[1] = fmaf(sval, wA.y, acc[1]);
        acc[2] = fmaf(sval, wA.z, acc[2]);
        acc[3] = fmaf(sval, wA.w, acc[3]);
        acc[4] = fmaf(sval, wB.x, acc[4]);
        acc[5] = fmaf(sval, wB.y, acc[5]);
        acc[6] = fmaf(sval, wB.z, acc[6]);
        acc[7] = fmaf(sval, wB.w, acc[7]);
      }
    }
  }

#pragma unroll
  for (int oi = 0; oi < 8; ++oi) {
    int o = ogu * 8 + oi;
    float rres = fmaf(acc[oi], bn[o], bn[64 + o]);
    out[((size_t)(b * 64 + o) << 14) + hw0 + pxl] = fmaxf(rres, 0.f);
  }
}

extern "C" void kernel_launch(void* const* d_in, const int* in_sizes, int n_in,
                              void* d_out, int out_size, void* d_ws, size_t ws_size,
                              hipStream_t stream) {
  const float* x      = (const float*)d_in[0];
  const float* w_off1 = (const float*)d_in[1];
  const float* b_off1 = (const float*)d_in[2];
  const float* w1     = (const float*)d_in[3];
  const float* g1     = (const float*)d_in[4];
  const float* be1    = (const float*)d_in[5];
  const float* m1     = (const float*)d_in[6];
  const float* v1     = (const float*)d_in[7];
  const float* w_off2 = (const float*)d_in[8];
  const float* b_off2 = (const float*)d_in[9];
  const float* w2     = (const float*)d_in[10];
  const float* g2     = (const float*)d_in[11];
  const float* be2    = (const float*)d_in[12];
  const float* m2     = (const float*)d_in[13];
  const float* v2     = (const float*)d_in[14];
  float* out = (float*)d_out;

  float* ws   = (float*)d_ws;
  float* wt1  = ws;
  float* wt2  = ws + 36864;
  float* wo1  = ws + 73728;
  float* wo2  = ws + 84096;
  float* bn1  = ws + 94464;
  float* bn2  = ws + 94592;
  float* offb = ws + 94720;
  float* hbuf = ws + 1274368;

  prep_kernel<<<370, 256, 0, stream>>>(w1, w2, w_off1, w_off2,
                                       g1, be1, m1, v1, g2, be2, m2, v2, ws);

  conv_off_kernel<<<1024, 512, 0, stream>>>(x, wo1, b_off1, offb);
  dcn_main_kernel<<<1024, 512, 0, stream>>>(x, offb, wt1, bn1, hbuf);

  conv_off_kernel<<<1024, 512, 0, stream>>>(hbuf, wo2, b_off2, offb);
  dcn_main_kernel<<<1024, 512, 0, stream>>>(hbuf, offb, wt2, bn2, out);
}

// Round 7
// 375.533 us; speedup vs baseline: 2.9425x; 1.1497x over previous
//
#include <hip/hip_runtime.h>

// B=4, Cin=Cout=64, H=W=128, K=9, PAD=1. NCHW fp32.
//
// lgkm-only barrier: LDS producer->consumer needs lgkmcnt(0) only; global
// prefetch loads stay in flight across it (vmcnt wait lands at the use).
#define BAR_LGKM()                                         \
  do {                                                     \
    asm volatile("s_waitcnt lgkmcnt(0)" ::: "memory");     \
    __builtin_amdgcn_s_barrier();                          \
  } while (0)

// XCD-aware swizzle: 1024 blocks, 8 XCDs, dispatch round-robins bid%8.
// Each XCD gets a contiguous 128-block chunk -> gather footprint ~2.4MB
// fits the XCD's 4MB L2. (Verified round 4: FETCH 52.6 MB -> 12.7 MB.)
__device__ __forceinline__ int swz_block(int bid) {
  return ((bid & 7) << 7) + (bid >> 3);
}

// Workspace layout (floats):
//   wt1  @ 0       (36864)  main weights layer1, [c][og][k][oi] (og=o/8, oi=o%8)
//   wt2  @ 36864   (36864)
//   wo1  @ 73728   (10368)  offset-conv weights layer1, [c][t][j] (j=0..17)
//   wo2  @ 84096   (10368)
//   bn1  @ 94464   (128)    scale[64], shift[64]
//   bn2  @ 94592   (128)
//   offb @ 94720   (1179648)  4*18*16384
//   hbuf @ 1274368 (4194304)  4*64*16384

// ---------------- prep: weight relayouts + BN constants ---------------------
__global__ __launch_bounds__(256) void prep_kernel(
    const float* __restrict__ w1, const float* __restrict__ w2,
    const float* __restrict__ woff1, const float* __restrict__ woff2,
    const float* __restrict__ g1, const float* __restrict__ be1,
    const float* __restrict__ m1, const float* __restrict__ v1,
    const float* __restrict__ g2, const float* __restrict__ be2,
    const float* __restrict__ m2, const float* __restrict__ v2,
    float* __restrict__ ws) {
  float* wt1 = ws;
  float* wt2 = ws + 36864;
  float* wo1 = ws + 73728;
  float* wo2 = ws + 84096;
  float* bn1 = ws + 94464;
  float* bn2 = ws + 94592;
  int idx = blockIdx.x * 256 + threadIdx.x;
  if (idx < 73728) {
    int t = (idx < 36864) ? idx : idx - 36864;
    const float* w = (idx < 36864) ? w1 : w2;
    float* wt = (idx < 36864) ? wt1 : wt2;
    int oi = t & 7;
    int rest = t >> 3;             // (c*8+og)*9 + k
    int k = rest % 9;
    int cog = rest / 9;
    int og = cog & 7, c = cog >> 3;
    int o = og * 8 + oi;
    wt[t] = w[(o * 64 + c) * 9 + k];
  } else if (idx < 94464) {
    int u = idx - 73728;
    int t2 = (u < 10368) ? u : u - 10368;
    const float* w = (u < 10368) ? woff1 : woff2;
    float* wo = (u < 10368) ? wo1 : wo2;
    int j = t2 % 18;
    int v = t2 / 18;               // c*9 + t
    int tt = v % 9;
    int c = v / 9;
    wo[t2] = w[(j * 64 + c) * 9 + tt];
  } else if (idx < 94528) {
    int o = idx - 94464;
    float s = g1[o] * rsqrtf(v1[o] + 1e-5f);
    bn1[o] = s;
    bn1[64 + o] = be1[o] - m1[o] * s;
  } else if (idx < 94592) {
    int o = idx - 94528;
    float s = g2[o] * rsqrtf(v2[o] + 1e-5f);
    bn2[o] = s;
    bn2[64 + o] = be2[o] - m2[o] * s;
  }
}

// ---------------- offset conv: 3x3, 64 -> 18 ch, zero pad -------------------
// (unchanged for clean A/B on dcn_main)
__global__ __launch_bounds__(512, 8) void conv_off_kernel(
    const float* __restrict__ xin, const float* __restrict__ wofft,
    const float* __restrict__ boff, float* __restrict__ off) {
  __shared__ float halo[2][792];   // [buf][plane*198 + pos], 4 planes/stage
  int tid = threadIdx.x;
  int pxl = tid & 63;
  int og = tid >> 6;
  int ogu = __builtin_amdgcn_readfirstlane(og);   // wave-uniform -> s_loads
  int p0 = swz_block(blockIdx.x) * 64;
  int b = p0 >> 14, hw0 = p0 & 16383;
  int h = hw0 >> 7, w0 = hw0 & 127;

  bool sv = tid < 396;
  int pp = (tid >= 198) ? 1 : 0;   // which of 2 plane-slots this thread loads
  int pos = tid - pp * 198;
  int r = pos / 66, cc = pos - r * 66;
  int yy = h + r - 1, xx = w0 + cc - 1;
  bool inb = sv && (yy >= 0) && (yy < 128) && (xx >= 0) && (xx < 128);
  int ofs = (yy << 7) + xx;        // plane-relative
  const float* xb0 = xin + ((size_t)(b * 64) << 14);

  // prologue: planes 0..3 (thread covers planes pp and 2+pp at its pos)
  float stg0 = inb ? xb0[((size_t)pp << 14) + ofs] : 0.f;
  float stg1 = inb ? xb0[((size_t)(2 + pp) << 14) + ofs] : 0.f;

  // j-channel assignment: og 0,1 -> 3 outputs; og 2..7 -> 2 outputs.
  int jbase = (ogu < 2) ? ogu * 3 : 6 + (ogu - 2) * 2;
  int nj = (ogu < 2) ? 3 : 2;
  int jc2 = jbase + 2;
  if (jc2 > 17) jc2 = 17;          // clamp (result unused when nj==2)

  float acc[3] = {0.f, 0.f, 0.f};

#pragma unroll 1
  for (int cg = 0; cg < 64; cg += 4) {
    int bufi = (cg >> 2) & 1;
    if (sv) {
      halo[bufi][pp * 198 + pos] = stg0;
      halo[bufi][(2 + pp) * 198 + pos] = stg1;
    }
    if (cg < 60) {
      stg0 = inb ? xb0[((size_t)(cg + 4 + pp) << 14) + ofs] : 0.f;
      stg1 = inb ? xb0[((size_t)(cg + 6 + pp) << 14) + ofs] : 0.f;
    }
    BAR_LGKM();
    const float* hb = halo[bufi];
#pragma unroll
    for (int p = 0; p < 4; ++p) {
      const float* wc = wofft + (cg + p) * 162;
#pragma unroll
      for (int t = 0; t < 9; ++t) {
        float v = hb[p * 198 + (t / 3) * 66 + pxl + (t % 3)];
        acc[0] = fmaf(v, wc[t * 18 + jbase], acc[0]);
        acc[1] = fmaf(v, wc[t * 18 + jbase + 1], acc[1]);
        acc[2] = fmaf(v, wc[t * 18 + jc2], acc[2]);
      }
    }
  }
#pragma unroll
  for (int i = 0; i < 3; ++i) {
    if (i < nj) {
      int j = jbase + i;
      off[((size_t)(b * 18 + j) << 14) + hw0 + pxl] = acc[i] + boff[j];
    }
  }
}

// ---------------- fused deformable sample + einsum + BN + ReLU --------------
// Round-3 structure (best measured: 118 us) + two exact VALU cuts:
//  (a) x-selects folded into bilinear coeffs: sample = qx*t0.x + qy*t0.y +
//      qu*t1.x + qv*t1.y  (4 FMA, 0 cndmask; selects are c-invariant)
//  (b) incrementing per-lane gather pointers (+plane stride per c) instead
//      of re-deriving 64-bit addresses every iteration.
// Weights via s_load (wave-uniform wt pointer); depth-1 tap prefetch in
// flight across the lgkm-only barrier; XCD swizzle for L2 residency.
__global__ __launch_bounds__(512, 8) void dcn_main_kernel(
    const float* __restrict__ xin, const float* __restrict__ off,
    const float* __restrict__ wt, const float* __restrict__ bn,
    float* __restrict__ out) {
  __shared__ float sbuf[2][576];
  int tid = threadIdx.x;
  int pxl = tid & 63;
  int og = tid >> 6;
  int ogu = __builtin_amdgcn_readfirstlane(og);
  int p0 = swz_block(blockIdx.x) * 64;
  int b = p0 >> 14, hw0 = p0 & 16383;
  int h = hw0 >> 7, w0 = hw0 & 127;
  const float* xb = xin + ((size_t)b << 20);

  bool act1 = (tid & 7) == 0;      // slot1 handled by 1/8 of threads
  int s1 = 512 + (tid >> 3);       // slot id 512..575 (k=8)

  // --- per-slot params: folded coeffs (x-select baked in) + row pointers ---
  float q[2][4];                   // [slot][{t0.x,t0.y,t1.x,t1.y} coeff]
  const float* pa[2];              // row y0 float2 base (per-lane), plane 0
  const float* pb[2];              // row y1

#pragma unroll
  for (int j = 0; j < 2; ++j) {
    bool a = (j == 0) || act1;
    int s = (j == 0) ? tid : s1;
    int k = s >> 6;
    int pxs = s & 63;
    int hw = hw0 + pxs;
    float dy = a ? off[((size_t)(b * 18 + 2 * k) << 14) + hw] : 0.f;
    float dx = a ? off[((size_t)(b * 18 + 2 * k + 1) << 14) + hw] : 0.f;
    float py = (float)(h + k / 3 - 1) + dy;
    float pxf = (float)(w0 + pxs + k % 3 - 1) + dx;
    float y0f = floorf(py), x0f = floorf(pxf);
    float wy1 = py - y0f, wx1 = pxf - x0f;
    float wy0 = 1.f - wy1, wx0 = 1.f - wx1;
    int y0 = (int)y0f, x0 = (int)x0f;
    int y1 = y0 + 1, x1 = x0 + 1;
    bool vy0 = (y0 >= 0) && (y0 <= 127);
    bool vy1 = (y1 >= 0) && (y1 <= 127);
    bool vx0 = (x0 >= 0) && (x0 <= 127);
    bool vx1 = (x1 >= 0) && (x1 <= 127);
    float pw0 = (vy0 && vx0) ? wy0 * wx0 : 0.f;
    float pw1 = (vy0 && vx1) ? wy0 * wx1 : 0.f;
    float pw2 = (vy1 && vx0) ? wy1 * wx0 : 0.f;
    float pw3 = (vy1 && vx1) ? wy1 * wx1 : 0.f;
    int y0c = min(max(y0, 0), 127), y1c = min(max(y1, 0), 127);
    int xb2 = min(max(x0, 0), 126);
    bool se0 = (x0 == xb2);        // tap(x0) is .x of the pair
    bool se1 = (x0 + 1 == xb2);    // tap(x0+1) is .x of the pair (x0==-1 case)
    // fold selects: coeff(.x) = se?pw ; coeff(.y) = !se?pw. Whenever the
    // "wrong" element is picked, the corresponding pw is already 0.
    q[j][0] = (se0 ? pw0 : 0.f) + (se1 ? pw1 : 0.f);
    q[j][1] = (se0 ? 0.f : pw0) + (se1 ? 0.f : pw1);
    q[j][2] = (se0 ? pw2 : 0.f) + (se1 ? pw3 : 0.f);
    q[j][3] = (se0 ? 0.f : pw2) + (se1 ? 0.f : pw3);
    pa[j] = xb + ((y0c << 7) + xb2);
    pb[j] = xb + ((y1c << 7) + xb2);
  }

  // prologue: taps for c=0; then advance pointers to plane 1
  float2 t0a = *(const float2*)pa[0];
  float2 t1a = *(const float2*)pb[0];
  float2 t0b = act1 ? *(const float2*)pa[1] : make_float2(0.f, 0.f);
  float2 t1b = act1 ? *(const float2*)pb[1] : make_float2(0.f, 0.f);
  pa[0] += 16384; pb[0] += 16384; pa[1] += 16384; pb[1] += 16384;

  float acc[8];
#pragma unroll
  for (int oi = 0; oi < 8; ++oi) acc[oi] = 0.f;

#pragma unroll 1
  for (int c = 0; c < 64; ++c) {
    // blend + stash to LDS (4 FMA, no selects)
    sbuf[c & 1][tid] = fmaf(q[0][0], t0a.x,
                       fmaf(q[0][1], t0a.y,
                       fmaf(q[0][2], t1a.x, q[0][3] * t1a.y)));
    if (act1) {
      sbuf[c & 1][s1] = fmaf(q[1][0], t0b.x,
                        fmaf(q[1][1], t0b.y,
                        fmaf(q[1][2], t1b.x, q[1][3] * t1b.y)));
    }
    // prefetch taps for c+1 (in flight across the lgkm barrier)
    if (c < 63) {
      t0a = *(const float2*)pa[0];
      t1a = *(const float2*)pb[0];
      if (act1) {
        t0b = *(const float2*)pa[1];
        t1b = *(const float2*)pb[1];
      }
      pa[0] += 16384; pb[0] += 16384; pa[1] += 16384; pb[1] += 16384;
    }
    BAR_LGKM();
    const float* wc = wt + (c * 8 + ogu) * 72;   // [c][og][k][8], s_load
#pragma unroll
    for (int k = 0; k < 9; ++k) {
      float sval = sbuf[c & 1][k * 64 + pxl];
#pragma unroll
      for (int oi = 0; oi < 8; ++oi)
        acc[oi] = fmaf(sval, wc[k * 8 + oi], acc[oi]);
    }
  }

#pragma unroll
  for (int oi = 0; oi < 8; ++oi) {
    int o = ogu * 8 + oi;
    float rres = fmaf(acc[oi], bn[o], bn[64 + o]);
    out[((size_t)(b * 64 + o) << 14) + hw0 + pxl] = fmaxf(rres, 0.f);
  }
}

extern "C" void kernel_launch(void* const* d_in, const int* in_sizes, int n_in,
                              void* d_out, int out_size, void* d_ws, size_t ws_size,
                              hipStream_t stream) {
  const float* x      = (const float*)d_in[0];
  const float* w_off1 = (const float*)d_in[1];
  const float* b_off1 = (const float*)d_in[2];
  const float* w1     = (const float*)d_in[3];
  const float* g1     = (const float*)d_in[4];
  const float* be1    = (const float*)d_in[5];
  const float* m1     = (const float*)d_in[6];
  const float* v1     = (const float*)d_in[7];
  const float* w_off2 = (const float*)d_in[8];
  const float* b_off2 = (const float*)d_in[9];
  const float* w2     = (const float*)d_in[10];
  const float* g2     = (const float*)d_in[11];
  const float* be2    = (const float*)d_in[12];
  const float* m2     = (const float*)d_in[13];
  const float* v2     = (const float*)d_in[14];
  float* out = (float*)d_out;

  float* ws   = (float*)d_ws;
  float* wt1  = ws;
  float* wt2  = ws + 36864;
  float* wo1  = ws + 73728;
  float* wo2  = ws + 84096;
  float* bn1  = ws + 94464;
  float* bn2  = ws + 94592;
  float* offb = ws + 94720;
  float* hbuf = ws + 1274368;

  prep_kernel<<<370, 256, 0, stream>>>(w1, w2, w_off1, w_off2,
                                       g1, be1, m1, v1, g2, be2, m2, v2, ws);

  conv_off_kernel<<<1024, 512, 0, stream>>>(x, wo1, b_off1, offb);
  dcn_main_kernel<<<1024, 512, 0, stream>>>(x, offb, wt1, bn1, hbuf);

  conv_off_kernel<<<1024, 512, 0, stream>>>(hbuf, wo2, b_off2, offb);
  dcn_main_kernel<<<1024, 512, 0, stream>>>(hbuf, offb, wt2, bn2, out);
}